// Round 7
// baseline (1335.984 us; speedup 1.0000x reference)
//
#include <hip/hip_runtime.h>
#include <hip/hip_bf16.h>

typedef __hip_bfloat16 bf16;
typedef __attribute__((ext_vector_type(8))) short s16x8;   // 8 bf16 (4 VGPR) MFMA A/B frag
typedef __attribute__((ext_vector_type(4))) float f32x4;   // MFMA C/D frag

__device__ __forceinline__ float b2f(bf16 x) { return __bfloat162float(x); }
__device__ __forceinline__ bf16 f2b(float x) { return __float2bfloat16(x); }

__device__ __forceinline__ void gld16(const void* g, void* l) {
  __builtin_amdgcn_global_load_lds((const __attribute__((address_space(1))) unsigned int*)g,
                                   (__attribute__((address_space(3))) unsigned int*)l,
                                   16, 0, 0);
}

// ---------------------------------------------------------------------------
// sentinel: unmistakable absmax if workspace too small (f32 out)
__global__ __launch_bounds__(256) void fill_sentinel(float* out, int n) {
  int idx = blockIdx.x * 256 + threadIdx.x;
  if (idx < n) out[idx] = 100.0f;
}

__global__ __launch_bounds__(64) void zero_zb(bf16* zb) {
  zb[threadIdx.x * 2] = f2b(0.f);
  zb[threadIdx.x * 2 + 1] = f2b(0.f);
}

// ---------------------------------------------------------------------------
// pack conv weights (f32 -> bf16): wpN[s][o][c]; wnp[p][t][ot][c][m]
__global__ __launch_bounds__(256) void pack_w(const float* __restrict__ c0w,
                                              const float* __restrict__ c1w,
                                              const float* __restrict__ lw,
                                              bf16* wp0, bf16* wp1, bf16* wp2, bf16* wnp) {
  const int SEG = 9 * 256 * 256;
  int idx = blockIdx.x * 256 + threadIdx.x;
  if (idx < 3 * SEG) {
    int which = idx / SEG, r = idx % SEG;
    int s = r >> 16, o = (r >> 8) & 255, c = r & 255;
    int ky = s / 3, kx = s - 3 * ky;
    if (which == 0)      wp0[r] = f2b(c0w[(((size_t)o * 768 + 256 + c) * 3 + ky) * 3 + kx]);
    else if (which == 1) wp1[r] = f2b(c1w[(((size_t)o * 256 + c) * 3 + ky) * 3 + kx]);
    else                 wp2[r] = f2b(lw [(((size_t)o * 256 + c) * 3 + ky) * 3 + kx]);
  } else {
    int r = idx - 3 * SEG;             // [p][t][ot][c][m]
    int m = r & 255, c = (r >> 8) & 255, tt = r >> 16;
    int ot = tt % 3, t2 = (tt / 3) % 3, p = tt / 9;
    int ky, kx, cin;
    if (p == 0) { kx = t2; ky = ot; cin = c; }        // node_i block
    else        { ky = t2; kx = ot; cin = 512 + c; }  // node_j block
    wnp[r] = f2b(c0w[(((size_t)m * 768 + cin) * 3 + ky) * 3 + kx]);
  }
}

// ---------------------------------------------------------------------------
// adapter 1x1 (one batch): E[i][j][m] = sum_c aw[m][c]*e[i][j][c] + ab[m]  (f32 in, bf16 out)
__global__ __launch_bounds__(256) void adapter_k(const float* __restrict__ e,
                                                 const float* __restrict__ aw,
                                                 const float* __restrict__ ab,
                                                 bf16* __restrict__ E) {
  int i = blockIdx.x;
  int m = threadIdx.x;
  __shared__ float se[256 * 7];
  const size_t rb = (size_t)i * (256 * 7);
  for (int idx = m; idx < 256 * 7; idx += 256) se[idx] = e[rb + idx];
  __syncthreads();
  float w[7];
#pragma unroll
  for (int c = 0; c < 7; ++c) w[c] = aw[m * 7 + c];
  float bias = ab[m];
  bf16* ob = E + (size_t)i * 65536 + m;
  for (int j = 0; j < 256; ++j) {
    const float* ej = se + j * 7;
    float a = bias;
#pragma unroll
    for (int c = 0; c < 7; ++c) a += w[c] * ej[c];
    ob[(size_t)j * 256] = f2b(a);
  }
}

// ---------------------------------------------------------------------------
// node terms: TT[p*3+t][pos][m] = sum_{ot,c} wnp[p][t][ot][c][m]*nd_pad[pos+ot-1][c]
// grid = p(2) x t(3) x chunk(64 of 4 positions) = 384 blocks
template <typename T>
__global__ __launch_bounds__(256) void node_terms(const T* __restrict__ nd,
                                                  const bf16* __restrict__ wnp,
                                                  float* __restrict__ TT) {
  int bid = blockIdx.x;
  int chunk = bid & 63;
  int t = (bid >> 6) % 3;
  int p = bid / 192;
  int tid = threadIdx.x;
  __shared__ float snd[6][256];
  int pos0 = chunk * 4;
  for (int idx = tid; idx < 6 * 256; idx += 256) {
    int r = idx >> 8, c = idx & 255;
    int gp = pos0 - 1 + r;
    snd[r][c] = (gp >= 0 && gp < 256) ? (float)nd[(size_t)gp * 256 + c] : 0.f;
  }
  __syncthreads();
  float acc[4] = {0.f, 0.f, 0.f, 0.f};
  const bf16* wb = wnp + (size_t)((p * 3 + t) * 3) * 65536 + tid;
  for (int c = 0; c < 256; ++c) {
    float w0 = b2f(wb[(size_t)c * 256]);
    float w1 = b2f(wb[(size_t)(65536 + c * 256)]);
    float w2 = b2f(wb[(size_t)(2 * 65536 + c * 256)]);
#pragma unroll
    for (int ii = 0; ii < 4; ++ii)   // acc[ii] += w_ot * nd[pos0+ii-1+ot]
      acc[ii] += w0 * snd[ii][c] + w1 * snd[ii + 1][c] + w2 * snd[ii + 2][c];
  }
  float* o = TT + (((size_t)(p * 3 + t) * 256 + pos0) * 256) + tid;
#pragma unroll
  for (int ii = 0; ii < 4; ++ii) o[(size_t)ii * 256] = acc[ii];
}

// ---------------------------------------------------------------------------
// implicit-GEMM 3x3 conv (one batch), 256->256 ch, act [i][j][m] bf16, zero pad.
// EPI: add node terms (+ boundary masks). F32OUT: write f32 (final edge output).
// XCD-aware swizzle (r5): bid&7 = XCD; contiguous 32-row i-band per XCD -> L2 reuse.
// r6: 2-phase double-buffered pipeline w/ counted vmcnt (T3min+T4): stage chunk
// t+1 into the other 32KB buffer, s_waitcnt vmcnt(8) (keeps the 8 new loads in
// flight, waits only chunk t's 8 issued one full compute-phase earlier), raw
// s_barrier (NOT __syncthreads -> no vmcnt(0) drain), compute, s_barrier.
template <int EPI, int F32OUT>
__global__ __launch_bounds__(256, 2)
void conv3x3_k(const bf16* __restrict__ inb, const bf16* __restrict__ wpack,
               const float* __restrict__ bias, void* __restrict__ outv,
               const float* __restrict__ TT, const bf16* __restrict__ zbuf) {
  __shared__ __align__(16) char lds[65536];  // [buf][ lB 16K | lA 16K ] x2
  const int bid = blockIdx.x;               // 1024 = xcd(8) x slot(128)
  const int xcd = bid & 7, slot = bid >> 3;
  const int i = (xcd << 5) + (slot >> 2);   // 32-row band per XCD
  const int ob = slot & 1, jb = (slot >> 1) & 1;
  const int tid = threadIdx.x;
  const int lane = tid & 63, wid = tid >> 6;
  const int wr = wid >> 1, wc = wid & 1;
  const int lo = lane & 15, hi = lane >> 4;

  f32x4 acc[4][4];
  const f32x4 z = {0.f, 0.f, 0.f, 0.f};
#pragma unroll
  for (int mi = 0; mi < 4; ++mi)
#pragma unroll
    for (int ni = 0; ni < 4; ++ni) acc[mi][ni] = z;

  const int xS = tid >> 3;   // staging pixel (row) within 32-row chunk
  const int Gs = tid & 7;    // staging 16B-granule slot

  // valid ky taps form a CONTIGUOUS s-range (only i=0 drops ky=0, i=255 drops ky=2)
  const int s_lo = (i == 0) ? 3 : 0;
  const int s_hi = (i == 255) ? 5 : 8;
  const int nt = (s_hi - s_lo + 1) * 4;     // chunks: 4 per tap (64 ch each)

  auto STAGE = [&](int t, int buf) {
    const int s = s_lo + (t >> 2);
    const int ky = s / 3, kx = s - 3 * ky;
    const size_t rowbase = (size_t)(i + ky - 1) * 65536;
    const int colbase = jb * 128 + kx - 1;
    const size_t wbase = ((size_t)s * 256 + ob * 128) * 256;
    const int cb = (t & 3) * 64;
    char* lBb = lds + buf * 32768;
    char* lAb = lBb + 16384;
#pragma unroll
    for (int ch = 0; ch < 4; ++ch) {
      const int x = ch * 32 + xS;
      const int c = colbase + x;
      const int sw = (Gs ^ (x & 7)) << 3;   // pre-swizzled source granule
      const int ldst = (ch * 256 + wid * 64) << 4;  // wave-uniform LDS dest
      const bf16* srcB = (c >= 0 && c <= 255)
          ? inb + rowbase + ((size_t)c << 8) + cb + sw
          : zbuf + sw;                       // OOB column -> zeros
      gld16(srcB, lBb + ldst);
      gld16(wpack + wbase + ((size_t)x << 8) + cb + sw, lAb + ldst);
    }
  };

  auto COMPUTE = [&](int buf) {
    const char* lBb = lds + buf * 32768;
    const char* lAb = lBb + 16384;
#pragma unroll
    for (int kk = 0; kk < 2; ++kk) {
      s16x8 af[4], bfr[4];
      const int g0 = kk * 4 + hi;
      const int gx = (g0 ^ (lo & 7)) << 4;
#pragma unroll
      for (int mi = 0; mi < 4; ++mi) {
        const int x = wr * 64 + mi * 16 + lo;
        af[mi] = *(const s16x8*)(lBb + x * 128 + gx);
      }
#pragma unroll
      for (int ni = 0; ni < 4; ++ni) {
        const int x = wc * 64 + ni * 16 + lo;
        bfr[ni] = *(const s16x8*)(lAb + x * 128 + gx);
      }
#pragma unroll
      for (int mi = 0; mi < 4; ++mi)
#pragma unroll
        for (int ni = 0; ni < 4; ++ni)
          acc[mi][ni] = __builtin_amdgcn_mfma_f32_16x16x32_bf16(af[mi], bfr[ni], acc[mi][ni], 0, 0, 0);
    }
  };

  STAGE(0, 0);                               // 8 loads in flight
  for (int t = 0; t < nt; ++t) {
    const int buf = t & 1;
    if (t + 1 < nt) {
      STAGE(t + 1, buf ^ 1);                 // +8 -> 16 in flight
      asm volatile("s_waitcnt vmcnt(8)" ::: "memory");  // wait chunk t's 8 only
    } else {
      asm volatile("s_waitcnt vmcnt(0)" ::: "memory");
    }
    __builtin_amdgcn_s_barrier();            // all waves' stage(t) landed
    asm volatile("" ::: "memory");
    COMPUTE(buf);
    asm volatile("" ::: "memory");
    __builtin_amdgcn_s_barrier();            // all waves done reading buf
  }

  // epilogue: D col(lane&15)->o, row((lane>>4)*4+r)->pixel j
  const int o_base = ob * 128 + wc * 64 + lo;
  const int j_base = jb * 128 + wr * 64 + hi * 4;
  bf16* orow = (bf16*)outv + (size_t)i * 65536;
  float* orowf = (float*)outv + (size_t)i * 65536;
#pragma unroll
  for (int ni = 0; ni < 4; ++ni) {
    const int o = o_base + ni * 16;
    const float bs = bias[o];
    float ni0 = 0.f, ni1 = 0.f, ni2 = 0.f;
    if (EPI) {
      const float* TI = TT + (size_t)i * 256 + o;     // p=0 (node_i), t=kx
      ni0 = TI[0]; ni1 = TI[65536]; ni2 = TI[2 * 65536];
    }
#pragma unroll
    for (int mi = 0; mi < 4; ++mi) {
#pragma unroll
      for (int r = 0; r < 4; ++r) {
        const int j = j_base + mi * 16 + r;
        float v = acc[mi][ni][r] + bs;
        if (EPI) {
          v += ni1 + (j > 0 ? ni0 : 0.f) + (j < 255 ? ni2 : 0.f);
          const float* TJ = TT + (size_t)3 * 65536 + (size_t)j * 256 + o;  // p=1, t=ky
          float nj0 = TJ[0], nj1 = TJ[65536], nj2 = TJ[2 * 65536];
          v += nj1 + (i > 0 ? nj0 : 0.f) + (i < 255 ? nj2 : 0.f);
        }
        v = fmaxf(v, 0.f);
        if (F32OUT) orowf[(size_t)j * 256 + o] = v;
        else        orow[(size_t)j * 256 + o] = f2b(v);
      }
    }
  }
}

// ---------------------------------------------------------------------------
// fused: att = leaky(1x1(feat)); coeff = softmax_j; nd[i][m] = sum_j coeff*feat
// F32OUT: write f32 final node output, else bf16 ND scratch.
template <int F32OUT>
__global__ __launch_bounds__(256) void att_wsum(const bf16* __restrict__ feat,
                                                const float* __restrict__ aw,
                                                const float* __restrict__ ab,
                                                bf16* __restrict__ ndb,
                                                float* __restrict__ ndf) {
  int i = blockIdx.x;
  int tid = threadIdx.x, lane = tid & 63, w = tid >> 6;
  __shared__ float s_aw[256];
  __shared__ float s_att[256];
  __shared__ float s_red[8];
  s_aw[tid] = aw[tid];
  __syncthreads();
  float a0 = s_aw[lane * 4], a1 = s_aw[lane * 4 + 1];
  float a2 = s_aw[lane * 4 + 2], a3 = s_aw[lane * 4 + 3];
  const bf16* fb = feat + (size_t)i * 65536;
  float abv = ab[0];
  for (int jj = 0; jj < 64; ++jj) {
    int j = w * 64 + jj;
    const bf16* f = fb + (size_t)j * 256 + lane * 4;
    float v = a0 * b2f(f[0]) + a1 * b2f(f[1]) + a2 * b2f(f[2]) + a3 * b2f(f[3]);
#pragma unroll
    for (int mk = 32; mk; mk >>= 1) v += __shfl_xor(v, mk);
    if (lane == 0) { float a = v + abv; s_att[j] = a > 0.f ? a : 0.01f * a; }
  }
  __syncthreads();
  float x = s_att[tid];
  float mx = x;
#pragma unroll
  for (int mk = 32; mk; mk >>= 1) mx = fmaxf(mx, __shfl_xor(mx, mk));
  if (lane == 0) s_red[w] = mx;
  __syncthreads();
  mx = fmaxf(fmaxf(s_red[0], s_red[1]), fmaxf(s_red[2], s_red[3]));
  float e = expf(x - mx);
  float sm = e;
#pragma unroll
  for (int mk = 32; mk; mk >>= 1) sm += __shfl_xor(sm, mk);
  if (lane == 0) s_red[4 + w] = sm;
  __syncthreads();
  sm = s_red[4] + s_red[5] + s_red[6] + s_red[7];
  __syncthreads();
  s_att[tid] = e / sm;
  __syncthreads();
  float acc = 0.f;
  for (int j = 0; j < 256; ++j) acc += s_att[j] * b2f(fb[(size_t)j * 256 + tid]);
  if (F32OUT) ndf[(size_t)i * 256 + tid] = acc;
  else        ndb[(size_t)i * 256 + tid] = f2b(acc);
}

// ---------------------------------------------------------------------------
extern "C" void kernel_launch(void* const* d_in, const int* in_sizes, int n_in,
                              void* d_out, int out_size, void* d_ws, size_t ws_size,
                              hipStream_t stream) {
  const float* edge_feats = (const float*)d_in[0];
  const float* node_feats = (const float*)d_in[1];
  const float* adapter_w  = (const float*)d_in[2];
  const float* adapter_b  = (const float*)d_in[3];
  const float* conv0_w    = (const float*)d_in[4];
  const float* conv0_b    = (const float*)d_in[5];
  const float* conv1_w    = (const float*)d_in[6];
  const float* conv1_b    = (const float*)d_in[7];
  const float* last_w     = (const float*)d_in[8];
  const float* last_b     = (const float*)d_in[9];
  const float* att_w      = (const float*)d_in[10];
  const float* att_b      = (const float*)d_in[11];
  float* out = (float*)d_out;

  char* ws = (char*)d_ws;
  size_t off = 0;
  bf16* Q   = (bf16*)(ws + off); off += (size_t)256 * 256 * 256 * 2;      // 33,554,432
  bf16* WP0 = (bf16*)(ws + off); off += (size_t)9 * 65536 * 2;
  bf16* WP1 = (bf16*)(ws + off); off += (size_t)9 * 65536 * 2;
  bf16* WP2 = (bf16*)(ws + off); off += (size_t)9 * 65536 * 2;
  bf16* WNP = (bf16*)(ws + off); off += (size_t)18 * 65536 * 2;           //  2,359,296
  float* TT = (float*)(ws + off); off += (size_t)2 * 3 * 65536 * 4;       //  1,572,864
  bf16* ND  = (bf16*)(ws + off); off += (size_t)65536 * 2;                //    131,072
  bf16* ZB  = (bf16*)(ws + off); off += 256;                              // known-safe total 41,156,864
  if (ws_size < off) {
    fill_sentinel<<<(out_size + 255) / 256, 256, 0, stream>>>(out, out_size);
    return;
  }

  zero_zb<<<1, 64, 0, stream>>>(ZB);
  pack_w<<<11520, 256, 0, stream>>>(conv0_w, conv1_w, last_w, WP0, WP1, WP2, WNP);

  for (int b = 0; b < 2; ++b) {
    // P: bf16 scratch inside the (f32) edge-out region of batch b (first 32MB of 64MB)
    bf16* P = (bf16*)(out + 131072 + (size_t)b * 16777216);
    float* edge_out = out + 131072 + (size_t)b * 16777216;
    float* node_out = out + (size_t)b * 65536;
    const float* eb = edge_feats + (size_t)b * 458752;
    const float* nb = node_feats + (size_t)b * 65536;

    adapter_k<<<256, 256, 0, stream>>>(eb, adapter_w, adapter_b, P);                  // E  @ P
    // block 1
    node_terms<float><<<384, 256, 0, stream>>>(nb, WNP, TT);
    conv3x3_k<1, 0><<<1024, 256, 0, stream>>>(P, WP0, conv0_b, Q, TT, ZB);            // A  @ Q
    conv3x3_k<0, 0><<<1024, 256, 0, stream>>>(Q, WP1, conv1_b, P, nullptr, ZB);       // B  @ P
    att_wsum<0><<<256, 256, 0, stream>>>(P, att_w, att_b, ND, nullptr);               // nd1 @ ND
    conv3x3_k<0, 0><<<1024, 256, 0, stream>>>(P, WP2, last_b, Q, nullptr, ZB);        // C  @ Q
    // block 2
    node_terms<bf16><<<384, 256, 0, stream>>>(ND, WNP, TT);
    conv3x3_k<1, 0><<<1024, 256, 0, stream>>>(Q, WP0, conv0_b, P, TT, ZB);            // D  @ P
    conv3x3_k<0, 0><<<1024, 256, 0, stream>>>(P, WP1, conv1_b, Q, nullptr, ZB);       // E2 @ Q
    att_wsum<1><<<256, 256, 0, stream>>>(Q, att_w, att_b, nullptr, node_out);         // node out (f32)
    conv3x3_k<0, 1><<<1024, 256, 0, stream>>>(Q, WP2, last_b, edge_out, nullptr, ZB); // edge out (f32)
  }
}

// Round 9
// 1247.898 us; speedup vs baseline: 1.0706x; 1.0706x over previous
//
#include <hip/hip_runtime.h>
#include <hip/hip_bf16.h>

typedef __hip_bfloat16 bf16;
typedef __attribute__((ext_vector_type(8))) short s16x8;   // 8 bf16 (4 VGPR) MFMA A/B frag
typedef __attribute__((ext_vector_type(4))) float f32x4;   // MFMA C/D frag

__device__ __forceinline__ float b2f(bf16 x) { return __bfloat162float(x); }
__device__ __forceinline__ bf16 f2b(float x) { return __float2bfloat16(x); }

__device__ __forceinline__ void gld16(const void* g, void* l) {
  __builtin_amdgcn_global_load_lds((const __attribute__((address_space(1))) unsigned int*)g,
                                   (__attribute__((address_space(3))) unsigned int*)l,
                                   16, 0, 0);
}

#define BARRIER() do { asm volatile("" ::: "memory"); \
                       __builtin_amdgcn_s_barrier();  \
                       asm volatile("" ::: "memory"); } while (0)

// ---------------------------------------------------------------------------
__global__ __launch_bounds__(256) void fill_sentinel(float* out, int n) {
  int idx = blockIdx.x * 256 + threadIdx.x;
  if (idx < n) out[idx] = 100.0f;
}

__global__ __launch_bounds__(64) void zero_zb(bf16* zb) {
  zb[threadIdx.x * 2] = f2b(0.f);
  zb[threadIdx.x * 2 + 1] = f2b(0.f);
}

// ---------------------------------------------------------------------------
// pack conv weights (f32 -> bf16): wpN[s][o][c]; wnp[p][t][ot][c][m]
__global__ __launch_bounds__(256) void pack_w(const float* __restrict__ c0w,
                                              const float* __restrict__ c1w,
                                              const float* __restrict__ lw,
                                              bf16* wp0, bf16* wp1, bf16* wp2, bf16* wnp) {
  const int SEG = 9 * 256 * 256;
  int idx = blockIdx.x * 256 + threadIdx.x;
  if (idx < 3 * SEG) {
    int which = idx / SEG, r = idx % SEG;
    int s = r >> 16, o = (r >> 8) & 255, c = r & 255;
    int ky = s / 3, kx = s - 3 * ky;
    if (which == 0)      wp0[r] = f2b(c0w[(((size_t)o * 768 + 256 + c) * 3 + ky) * 3 + kx]);
    else if (which == 1) wp1[r] = f2b(c1w[(((size_t)o * 256 + c) * 3 + ky) * 3 + kx]);
    else                 wp2[r] = f2b(lw [(((size_t)o * 256 + c) * 3 + ky) * 3 + kx]);
  } else {
    int r = idx - 3 * SEG;             // [p][t][ot][c][m]
    int m = r & 255, c = (r >> 8) & 255, tt = r >> 16;
    int ot = tt % 3, t2 = (tt / 3) % 3, p = tt / 9;
    int ky, kx, cin;
    if (p == 0) { kx = t2; ky = ot; cin = c; }        // node_i block
    else        { ky = t2; kx = ot; cin = 512 + c; }  // node_j block
    wnp[r] = f2b(c0w[(((size_t)m * 768 + cin) * 3 + ky) * 3 + kx]);
  }
}

// ---------------------------------------------------------------------------
// adapter 1x1 (one batch): E[i][j][m] = sum_c aw[m][c]*e[i][j][c] + ab[m]
__global__ __launch_bounds__(256) void adapter_k(const float* __restrict__ e,
                                                 const float* __restrict__ aw,
                                                 const float* __restrict__ ab,
                                                 bf16* __restrict__ E) {
  int i = blockIdx.x;
  int m = threadIdx.x;
  __shared__ float se[256 * 7];
  const size_t rb = (size_t)i * (256 * 7);
  for (int idx = m; idx < 256 * 7; idx += 256) se[idx] = e[rb + idx];
  __syncthreads();
  float w[7];
#pragma unroll
  for (int c = 0; c < 7; ++c) w[c] = aw[m * 7 + c];
  float bias = ab[m];
  bf16* ob = E + (size_t)i * 65536 + m;
  for (int j = 0; j < 256; ++j) {
    const float* ej = se + j * 7;
    float a = bias;
#pragma unroll
    for (int c = 0; c < 7; ++c) a += w[c] * ej[c];
    ob[(size_t)j * 256] = f2b(a);
  }
}

// ---------------------------------------------------------------------------
// node terms: TT[p*3+t][pos][m]; grid = p(2) x t(3) x chunk(64 of 4 positions)
template <typename T>
__global__ __launch_bounds__(256) void node_terms(const T* __restrict__ nd,
                                                  const bf16* __restrict__ wnp,
                                                  float* __restrict__ TT) {
  int bid = blockIdx.x;
  int chunk = bid & 63;
  int t = (bid >> 6) % 3;
  int p = bid / 192;
  int tid = threadIdx.x;
  __shared__ float snd[6][256];
  int pos0 = chunk * 4;
  for (int idx = tid; idx < 6 * 256; idx += 256) {
    int r = idx >> 8, c = idx & 255;
    int gp = pos0 - 1 + r;
    snd[r][c] = (gp >= 0 && gp < 256) ? (float)nd[(size_t)gp * 256 + c] : 0.f;
  }
  __syncthreads();
  float acc[4] = {0.f, 0.f, 0.f, 0.f};
  const bf16* wb = wnp + (size_t)((p * 3 + t) * 3) * 65536 + tid;
  for (int c = 0; c < 256; ++c) {
    float w0 = b2f(wb[(size_t)c * 256]);
    float w1 = b2f(wb[(size_t)(65536 + c * 256)]);
    float w2 = b2f(wb[(size_t)(2 * 65536 + c * 256)]);
#pragma unroll
    for (int ii = 0; ii < 4; ++ii)
      acc[ii] += w0 * snd[ii][c] + w1 * snd[ii + 1][c] + w2 * snd[ii + 2][c];
  }
  float* o = TT + (((size_t)(p * 3 + t) * 256 + pos0) * 256) + tid;
#pragma unroll
  for (int ii = 0; ii < 4; ++ii) o[(size_t)ii * 256] = acc[ii];
}

// ---------------------------------------------------------------------------
// 256x256-tile 4-phase pipelined implicit-GEMM 3x3 conv (m201-style schedule).
// One block per output row i: M=256 px (j), N=256 oc, K=taps*256 in 64-ch tiles.
// 512 thr / 8 waves (2M x 4N); per wave 128px x 64oc; LDS 2dbuf x (32K in+32K w).
// RACE FIX (r8->r9): AF mapping x = mh*128 + wr*64 (phase order == staging
// order). ph1 reads IN rounds 0/1 (guaranteed by kt-1's ph4 vmcnt(2) gate +
// barrier); ph3 reads rounds 2/3 (guaranteed by ph2 vmcnt(4) gate + barrier).
// r8's x = wr*128 + mh*64 had wr=1 waves reading round 2 at ph1 -- one gate
// early -> sporadic stale reads (absmax 6.6e-2).
template <int EPI, int F32OUT>
__global__ __launch_bounds__(512, 1)
void conv3x3_k(const bf16* __restrict__ inb, const bf16* __restrict__ wpack,
               const float* __restrict__ bias, void* __restrict__ outv,
               const float* __restrict__ TT, const bf16* __restrict__ zbuf) {
  __shared__ __align__(16) char lds[131072];  // 2 x (32KB input | 32KB weights)
  const int bid = blockIdx.x;                 // 256 = xcd(8) x slot(32)
  const int i = ((bid & 7) << 5) + (bid >> 3);  // 32-row band per XCD
  const int tid = threadIdx.x;
  const int lane = tid & 63, wid = tid >> 6;
  const int wr = wid >> 2, wc = wid & 3;      // 2M x 4N wave grid
  const int lo = lane & 15, hi = lane >> 4;
  const int Gs = tid & 7;

  f32x4 acc00[4][2], acc01[4][2], acc10[4][2], acc11[4][2];
  const f32x4 z = {0.f, 0.f, 0.f, 0.f};
#pragma unroll
  for (int mf = 0; mf < 4; ++mf)
#pragma unroll
    for (int nf = 0; nf < 2; ++nf) { acc00[mf][nf] = z; acc01[mf][nf] = z;
                                     acc10[mf][nf] = z; acc11[mf][nf] = z; }
  s16x8 af[4][2], bfr[2][2];

  // valid ky taps are a contiguous s-range (i=0 drops ky=0, i=255 drops ky=2)
  const int s_lo = (i == 0) ? 3 : 0;
  const int s_hi = (i == 255) ? 5 : 8;
  const int nt = (s_hi - s_lo + 1) * 4;       // K-tiles of 64 ch

  auto STAGE_IN = [&](int t, int r) {         // input round r: px x=r*64+tid/8
    const int s = s_lo + (t >> 2);
    const int ky = s / 3, kx = s - 3 * ky;
    const int cb = (t & 3) * 64;
    const int x = r * 64 + (tid >> 3);
    const int j = x + kx - 1;
    const int sw = (Gs ^ (x & 7)) << 3;
    const bf16* src = (j >= 0 && j <= 255)
        ? inb + (size_t)(i + ky - 1) * 65536 + ((size_t)j << 8) + cb + sw
        : zbuf + sw;
    gld16(src, lds + (t & 1) * 65536 + ((r * 64 + wid * 8) << 7));
  };
  auto STAGE_W = [&](int t, int r) {          // weight round r: oc o=r*64+tid/8
    const int s = s_lo + (t >> 2);
    const int cb = (t & 3) * 64;
    const int o = r * 64 + (tid >> 3);
    gld16(wpack + ((size_t)(s * 256 + o) << 8) + cb + ((Gs ^ (o & 7)) << 3),
          lds + (t & 1) * 65536 + 32768 + ((r * 64 + wid * 8) << 7));
  };
  auto LD_AF = [&](int buf, int mh) {         // RACE FIX: rounds mh*2 + wr
#pragma unroll
    for (int mf = 0; mf < 4; ++mf)
#pragma unroll
      for (int kk = 0; kk < 2; ++kk) {
        const int x = mh * 128 + wr * 64 + mf * 16 + lo;
        af[mf][kk] = *(const s16x8*)(lds + buf * 65536 + x * 128 +
                                     (((kk * 4 + hi) ^ (lo & 7)) << 4));
      }
  };
  auto LD_BF = [&](int buf, int nh) {
#pragma unroll
    for (int nf = 0; nf < 2; ++nf)
#pragma unroll
      for (int kk = 0; kk < 2; ++kk) {
        const int o = wc * 64 + nh * 32 + nf * 16 + lo;
        bfr[nf][kk] = *(const s16x8*)(lds + buf * 65536 + 32768 + o * 128 +
                                      (((kk * 4 + hi) ^ (lo & 7)) << 4));
      }
  };

#define MMA_Q(ACC)                                                            \
  __builtin_amdgcn_s_setprio(1);                                              \
  _Pragma("unroll") for (int mf = 0; mf < 4; ++mf)                            \
  _Pragma("unroll") for (int nf = 0; nf < 2; ++nf)                            \
  _Pragma("unroll") for (int kk = 0; kk < 2; ++kk)                            \
    ACC[mf][nf] = __builtin_amdgcn_mfma_f32_16x16x32_bf16(                    \
        af[mf][kk], bfr[nf][kk], ACC[mf][nf], 0, 0, 0);                       \
  __builtin_amdgcn_s_setprio(0);

  // prologue: fully stage K-tile 0
#pragma unroll
  for (int r = 0; r < 4; ++r) { STAGE_IN(0, r); STAGE_W(0, r); }
  asm volatile("s_waitcnt vmcnt(0)" ::: "memory");
  BARRIER();

  for (int kt = 0; kt < nt; ++kt) {
    const int buf = kt & 1;
    const bool pf = (kt + 1 < nt);
    // phase 1: quadrant (mh0,nh0) -- reads IN rounds 0/1 (guaranteed)
    LD_AF(buf, 0); LD_BF(buf, 0);
    if (pf) { STAGE_W(kt + 1, 0); STAGE_W(kt + 1, 1); }
    BARRIER();
    MMA_Q(acc00);
    // phase 2: (mh0,nh1)
    LD_BF(buf, 1);
    if (pf) { STAGE_W(kt + 1, 2); STAGE_W(kt + 1, 3); }
    if (pf) asm volatile("s_waitcnt vmcnt(4)" ::: "memory");   // IN r2,r3 of kt landed
    else    asm volatile("s_waitcnt vmcnt(0)" ::: "memory");
    BARRIER();
    MMA_Q(acc01);
    // phase 3: (mh1,nh0) -- reads IN rounds 2/3 (guaranteed by ph2 gate)
    LD_AF(buf, 1); LD_BF(buf, 0);
    if (pf) { STAGE_IN(kt + 1, 0); STAGE_IN(kt + 1, 1); }
    BARRIER();
    MMA_Q(acc10);
    // phase 4: (mh1,nh1)
    LD_BF(buf, 1);
    if (pf) { STAGE_IN(kt + 1, 2); STAGE_IN(kt + 1, 3); }
    if (pf) asm volatile("s_waitcnt vmcnt(2)" ::: "memory");   // kt+1 W+IN01 landed
    else    asm volatile("s_waitcnt vmcnt(0)" ::: "memory");
    BARRIER();
    MMA_Q(acc11);
  }
#undef MMA_Q

  // epilogue: px j = MH*128 + wr*64 + mf*16 + hi*4 + rr (matches LD_AF fix)
  bf16* orow = (bf16*)outv + (size_t)i * 65536;
  float* orowf = (float*)outv + (size_t)i * 65536;
#define EPI_Q(ACC, MH, NH)                                                    \
  _Pragma("unroll") for (int mf = 0; mf < 4; ++mf) {                          \
    _Pragma("unroll") for (int nf = 0; nf < 2; ++nf) {                        \
      const int o = wc * 64 + NH * 32 + nf * 16 + lo;                         \
      const float bs = bias[o];                                               \
      float ni0 = 0.f, ni1 = 0.f, ni2 = 0.f;                                  \
      if (EPI) { const float* TI = TT + (size_t)i * 256 + o;                  \
        ni0 = TI[0]; ni1 = TI[65536]; ni2 = TI[2 * 65536]; }                  \
      _Pragma("unroll") for (int rr = 0; rr < 4; ++rr) {                      \
        const int j = MH * 128 + wr * 64 + mf * 16 + hi * 4 + rr;             \
        float v = ACC[mf][nf][rr] + bs;                                       \
        if (EPI) {                                                            \
          v += ni1 + (j > 0 ? ni0 : 0.f) + (j < 255 ? ni2 : 0.f);             \
          const float* TJ = TT + (size_t)3 * 65536 + (size_t)j * 256 + o;     \
          float nj0 = TJ[0], nj1 = TJ[65536], nj2 = TJ[2 * 65536];            \
          v += nj1 + (i > 0 ? nj0 : 0.f) + (i < 255 ? nj2 : 0.f); }           \
        v = fmaxf(v, 0.f);                                                    \
        if (F32OUT) orowf[(size_t)j * 256 + o] = v;                           \
        else        orow[(size_t)j * 256 + o] = f2b(v);                       \
      } } }
  EPI_Q(acc00, 0, 0); EPI_Q(acc01, 0, 1); EPI_Q(acc10, 1, 0); EPI_Q(acc11, 1, 1);
#undef EPI_Q
}

// ---------------------------------------------------------------------------
// fused: att = leaky(1x1(feat)); coeff = softmax_j; nd[i][m] = sum_j coeff*feat
template <int F32OUT>
__global__ __launch_bounds__(256) void att_wsum(const bf16* __restrict__ feat,
                                                const float* __restrict__ aw,
                                                const float* __restrict__ ab,
                                                bf16* __restrict__ ndb,
                                                float* __restrict__ ndf) {
  int i = blockIdx.x;
  int tid = threadIdx.x, lane = tid & 63, w = tid >> 6;
  __shared__ float s_aw[256];
  __shared__ float s_att[256];
  __shared__ float s_red[8];
  s_aw[tid] = aw[tid];
  __syncthreads();
  float a0 = s_aw[lane * 4], a1 = s_aw[lane * 4 + 1];
  float a2 = s_aw[lane * 4 + 2], a3 = s_aw[lane * 4 + 3];
  const bf16* fb = feat + (size_t)i * 65536;
  float abv = ab[0];
  for (int jj = 0; jj < 64; ++jj) {
    int j = w * 64 + jj;
    const bf16* f = fb + (size_t)j * 256 + lane * 4;
    float v = a0 * b2f(f[0]) + a1 * b2f(f[1]) + a2 * b2f(f[2]) + a3 * b2f(f[3]);
#pragma unroll
    for (int mk = 32; mk; mk >>= 1) v += __shfl_xor(v, mk);
    if (lane == 0) { float a = v + abv; s_att[j] = a > 0.f ? a : 0.01f * a; }
  }
  __syncthreads();
  float x = s_att[tid];
  float mx = x;
#pragma unroll
  for (int mk = 32; mk; mk >>= 1) mx = fmaxf(mx, __shfl_xor(mx, mk));
  if (lane == 0) s_red[w] = mx;
  __syncthreads();
  mx = fmaxf(fmaxf(s_red[0], s_red[1]), fmaxf(s_red[2], s_red[3]));
  float e = expf(x - mx);
  float sm = e;
#pragma unroll
  for (int mk = 32; mk; mk >>= 1) sm += __shfl_xor(sm, mk);
  if (lane == 0) s_red[4 + w] = sm;
  __syncthreads();
  sm = s_red[4] + s_red[5] + s_red[6] + s_red[7];
  __syncthreads();
  s_att[tid] = e / sm;
  __syncthreads();
  float acc = 0.f;
  for (int j = 0; j < 256; ++j) acc += s_att[j] * b2f(fb[(size_t)j * 256 + tid]);
  if (F32OUT) ndf[(size_t)i * 256 + tid] = acc;
  else        ndb[(size_t)i * 256 + tid] = f2b(acc);
}

// ---------------------------------------------------------------------------
extern "C" void kernel_launch(void* const* d_in, const int* in_sizes, int n_in,
                              void* d_out, int out_size, void* d_ws, size_t ws_size,
                              hipStream_t stream) {
  const float* edge_feats = (const float*)d_in[0];
  const float* node_feats = (const float*)d_in[1];
  const float* adapter_w  = (const float*)d_in[2];
  const float* adapter_b  = (const float*)d_in[3];
  const float* conv0_w    = (const float*)d_in[4];
  const float* conv0_b    = (const float*)d_in[5];
  const float* conv1_w    = (const float*)d_in[6];
  const float* conv1_b    = (const float*)d_in[7];
  const float* last_w     = (const float*)d_in[8];
  const float* last_b     = (const float*)d_in[9];
  const float* att_w      = (const float*)d_in[10];
  const float* att_b      = (const float*)d_in[11];
  float* out = (float*)d_out;

  char* ws = (char*)d_ws;
  size_t off = 0;
  bf16* Q   = (bf16*)(ws + off); off += (size_t)256 * 256 * 256 * 2;      // 33,554,432
  bf16* WP0 = (bf16*)(ws + off); off += (size_t)9 * 65536 * 2;
  bf16* WP1 = (bf16*)(ws + off); off += (size_t)9 * 65536 * 2;
  bf16* WP2 = (bf16*)(ws + off); off += (size_t)9 * 65536 * 2;
  bf16* WNP = (bf16*)(ws + off); off += (size_t)18 * 65536 * 2;           //  2,359,296
  float* TT = (float*)(ws + off); off += (size_t)2 * 3 * 65536 * 4;       //  1,572,864
  bf16* ND  = (bf16*)(ws + off); off += (size_t)65536 * 2;                //    131,072
  bf16* ZB  = (bf16*)(ws + off); off += 256;                              // known-safe total 41,156,864
  if (ws_size < off) {
    fill_sentinel<<<(out_size + 255) / 256, 256, 0, stream>>>(out, out_size);
    return;
  }

  zero_zb<<<1, 64, 0, stream>>>(ZB);
  pack_w<<<11520, 256, 0, stream>>>(conv0_w, conv1_w, last_w, WP0, WP1, WP2, WNP);

  for (int b = 0; b < 2; ++b) {
    // P: bf16 scratch inside the (f32) edge-out region of batch b
    bf16* P = (bf16*)(out + 131072 + (size_t)b * 16777216);
    float* edge_out = out + 131072 + (size_t)b * 16777216;
    float* node_out = out + (size_t)b * 65536;
    const float* eb = edge_feats + (size_t)b * 458752;
    const float* nb = node_feats + (size_t)b * 65536;

    adapter_k<<<256, 256, 0, stream>>>(eb, adapter_w, adapter_b, P);                 // E  @ P
    // block 1
    node_terms<float><<<384, 256, 0, stream>>>(nb, WNP, TT);
    conv3x3_k<1, 0><<<256, 512, 0, stream>>>(P, WP0, conv0_b, Q, TT, ZB);            // A  @ Q
    conv3x3_k<0, 0><<<256, 512, 0, stream>>>(Q, WP1, conv1_b, P, nullptr, ZB);       // B  @ P
    att_wsum<0><<<256, 256, 0, stream>>>(P, att_w, att_b, ND, nullptr);              // nd1 @ ND
    conv3x3_k<0, 0><<<256, 512, 0, stream>>>(P, WP2, last_b, Q, nullptr, ZB);        // C  @ Q
    // block 2
    node_terms<bf16><<<384, 256, 0, stream>>>(ND, WNP, TT);
    conv3x3_k<1, 0><<<256, 512, 0, stream>>>(Q, WP0, conv0_b, P, TT, ZB);            // D  @ P
    conv3x3_k<0, 0><<<256, 512, 0, stream>>>(P, WP1, conv1_b, Q, nullptr, ZB);       // E2 @ Q
    att_wsum<1><<<256, 256, 0, stream>>>(Q, att_w, att_b, nullptr, node_out);        // node out (f32)
    conv3x3_k<0, 1><<<256, 512, 0, stream>>>(Q, WP2, last_b, edge_out, nullptr, ZB); // edge out (f32)
  }
}

// Round 10
// 1193.225 us; speedup vs baseline: 1.1196x; 1.0458x over previous
//
#include <hip/hip_runtime.h>
#include <hip/hip_bf16.h>

typedef __hip_bfloat16 bf16;
typedef __attribute__((ext_vector_type(8))) short s16x8;   // 8 bf16 (4 VGPR) MFMA A/B frag
typedef __attribute__((ext_vector_type(4))) float f32x4;   // MFMA C/D frag

__device__ __forceinline__ float b2f(bf16 x) { return __bfloat162float(x); }
__device__ __forceinline__ bf16 f2b(float x) { return __float2bfloat16(x); }

__device__ __forceinline__ void gld16(const void* g, void* l) {
  __builtin_amdgcn_global_load_lds((const __attribute__((address_space(1))) unsigned int*)g,
                                   (__attribute__((address_space(3))) unsigned int*)l,
                                   16, 0, 0);
}

#define BARRIER() do { asm volatile("" ::: "memory"); \
                       __builtin_amdgcn_s_barrier();  \
                       asm volatile("" ::: "memory"); } while (0)

// ---------------------------------------------------------------------------
__global__ __launch_bounds__(256) void fill_sentinel(float* out, int n) {
  int idx = blockIdx.x * 256 + threadIdx.x;
  if (idx < n) out[idx] = 100.0f;
}

__global__ __launch_bounds__(64) void zero_zb(bf16* zb) {
  zb[threadIdx.x * 2] = f2b(0.f);
  zb[threadIdx.x * 2 + 1] = f2b(0.f);
}

// ---------------------------------------------------------------------------
// pack conv weights (f32 -> bf16): wpN[s][o][c]; wnp[p][t][ot][c][m]
__global__ __launch_bounds__(256) void pack_w(const float* __restrict__ c0w,
                                              const float* __restrict__ c1w,
                                              const float* __restrict__ lw,
                                              bf16* wp0, bf16* wp1, bf16* wp2, bf16* wnp) {
  const int SEG = 9 * 256 * 256;
  int idx = blockIdx.x * 256 + threadIdx.x;
  if (idx < 3 * SEG) {
    int which = idx / SEG, r = idx % SEG;
    int s = r >> 16, o = (r >> 8) & 255, c = r & 255;
    int ky = s / 3, kx = s - 3 * ky;
    if (which == 0)      wp0[r] = f2b(c0w[(((size_t)o * 768 + 256 + c) * 3 + ky) * 3 + kx]);
    else if (which == 1) wp1[r] = f2b(c1w[(((size_t)o * 256 + c) * 3 + ky) * 3 + kx]);
    else                 wp2[r] = f2b(lw [(((size_t)o * 256 + c) * 3 + ky) * 3 + kx]);
  } else {
    int r = idx - 3 * SEG;             // [p][t][ot][c][m]
    int m = r & 255, c = (r >> 8) & 255, tt = r >> 16;
    int ot = tt % 3, t2 = (tt / 3) % 3, p = tt / 9;
    int ky, kx, cin;
    if (p == 0) { kx = t2; ky = ot; cin = c; }        // node_i block
    else        { ky = t2; kx = ot; cin = 512 + c; }  // node_j block
    wnp[r] = f2b(c0w[(((size_t)m * 768 + cin) * 3 + ky) * 3 + kx]);
  }
}

// ---------------------------------------------------------------------------
// adapter 1x1 (one batch): E[i][j][m] = sum_c aw[m][c]*e[i][j][c] + ab[m]
__global__ __launch_bounds__(256) void adapter_k(const float* __restrict__ e,
                                                 const float* __restrict__ aw,
                                                 const float* __restrict__ ab,
                                                 bf16* __restrict__ E) {
  int i = blockIdx.x;
  int m = threadIdx.x;
  __shared__ float se[256 * 7];
  const size_t rb = (size_t)i * (256 * 7);
  for (int idx = m; idx < 256 * 7; idx += 256) se[idx] = e[rb + idx];
  __syncthreads();
  float w[7];
#pragma unroll
  for (int c = 0; c < 7; ++c) w[c] = aw[m * 7 + c];
  float bias = ab[m];
  bf16* ob = E + (size_t)i * 65536 + m;
  for (int j = 0; j < 256; ++j) {
    const float* ej = se + j * 7;
    float a = bias;
#pragma unroll
    for (int c = 0; c < 7; ++c) a += w[c] * ej[c];
    ob[(size_t)j * 256] = f2b(a);
  }
}

// ---------------------------------------------------------------------------
// node terms: TT[p*3+t][pos][m]; grid = p(2) x t(3) x chunk(64 of 4 positions)
template <typename T>
__global__ __launch_bounds__(256) void node_terms(const T* __restrict__ nd,
                                                  const bf16* __restrict__ wnp,
                                                  float* __restrict__ TT) {
  int bid = blockIdx.x;
  int chunk = bid & 63;
  int t = (bid >> 6) % 3;
  int p = bid / 192;
  int tid = threadIdx.x;
  __shared__ float snd[6][256];
  int pos0 = chunk * 4;
  for (int idx = tid; idx < 6 * 256; idx += 256) {
    int r = idx >> 8, c = idx & 255;
    int gp = pos0 - 1 + r;
    snd[r][c] = (gp >= 0 && gp < 256) ? (float)nd[(size_t)gp * 256 + c] : 0.f;
  }
  __syncthreads();
  float acc[4] = {0.f, 0.f, 0.f, 0.f};
  const bf16* wb = wnp + (size_t)((p * 3 + t) * 3) * 65536 + tid;
  for (int c = 0; c < 256; ++c) {
    float w0 = b2f(wb[(size_t)c * 256]);
    float w1 = b2f(wb[(size_t)(65536 + c * 256)]);
    float w2 = b2f(wb[(size_t)(2 * 65536 + c * 256)]);
#pragma unroll
    for (int ii = 0; ii < 4; ++ii)
      acc[ii] += w0 * snd[ii][c] + w1 * snd[ii + 1][c] + w2 * snd[ii + 2][c];
  }
  float* o = TT + (((size_t)(p * 3 + t) * 256 + pos0) * 256) + tid;
#pragma unroll
  for (int ii = 0; ii < 4; ++ii) o[(size_t)ii * 256] = acc[ii];
}

// ---------------------------------------------------------------------------
// 256x256-tile 4-phase pipelined implicit-GEMM 3x3 conv.
// r10: DEEP-SLACK staging -- all 4 W loads at ph1, all 4 IN loads at ph2
// (kt+1). Ledger per wave (oldest->newest): W0..3,IN0,IN1,IN2,IN3.
//   ph2 gate vmcnt(8): waits IN r2,r3 of kt (issued ~6 phases ago, free);
//   ph4 gate vmcnt(2): waits W0-3 (~3 ph) + IN r0,r1 (~2 ph >= 1200 cyc)
//   -> every gated load has >=1200 cyc cover (HBM-miss tolerant; r9's
//   tightest was ~600 cyc -> gate stalls when L2 thrashes, FETCH 84MB).
// B-fragments bfr0/bfr1 held in registers across phases (ds_read 32->24/K-tile).
template <int EPI, int F32OUT>
__global__ __launch_bounds__(512, 1)
void conv3x3_k(const bf16* __restrict__ inb, const bf16* __restrict__ wpack,
               const float* __restrict__ bias, void* __restrict__ outv,
               const float* __restrict__ TT, const bf16* __restrict__ zbuf) {
  __shared__ __align__(16) char lds[131072];  // 2 x (32KB input | 32KB weights)
  const int bid = blockIdx.x;                 // 256 = xcd(8) x slot(32)
  const int i = ((bid & 7) << 5) + (bid >> 3);  // 32-row band per XCD
  const int tid = threadIdx.x;
  const int lane = tid & 63, wid = tid >> 6;
  const int wr = wid >> 2, wc = wid & 3;      // 2M x 4N wave grid
  const int lo = lane & 15, hi = lane >> 4;
  const int Gs = tid & 7;

  f32x4 acc00[4][2], acc01[4][2], acc10[4][2], acc11[4][2];
  const f32x4 z = {0.f, 0.f, 0.f, 0.f};
#pragma unroll
  for (int mf = 0; mf < 4; ++mf)
#pragma unroll
    for (int nf = 0; nf < 2; ++nf) { acc00[mf][nf] = z; acc01[mf][nf] = z;
                                     acc10[mf][nf] = z; acc11[mf][nf] = z; }
  s16x8 af[4][2], bfr0[2][2], bfr1[2][2];

  // valid ky taps are a contiguous s-range (i=0 drops ky=0, i=255 drops ky=2)
  const int s_lo = (i == 0) ? 3 : 0;
  const int s_hi = (i == 255) ? 5 : 8;
  const int nt = (s_hi - s_lo + 1) * 4;       // K-tiles of 64 ch

  auto STAGE_IN = [&](int t, int r) {         // input round r: px x=r*64+tid/8
    const int s = s_lo + (t >> 2);
    const int ky = s / 3, kx = s - 3 * ky;
    const int cb = (t & 3) * 64;
    const int x = r * 64 + (tid >> 3);
    const int j = x + kx - 1;
    const int sw = (Gs ^ (x & 7)) << 3;
    const bf16* src = (j >= 0 && j <= 255)
        ? inb + (size_t)(i + ky - 1) * 65536 + ((size_t)j << 8) + cb + sw
        : zbuf + sw;
    gld16(src, lds + (t & 1) * 65536 + ((r * 64 + wid * 8) << 7));
  };
  auto STAGE_W = [&](int t, int r) {          // weight round r: oc o=r*64+tid/8
    const int s = s_lo + (t >> 2);
    const int cb = (t & 3) * 64;
    const int o = r * 64 + (tid >> 3);
    gld16(wpack + ((size_t)(s * 256 + o) << 8) + cb + ((Gs ^ (o & 7)) << 3),
          lds + (t & 1) * 65536 + 32768 + ((r * 64 + wid * 8) << 7));
  };
  auto LD_AF = [&](int buf, int mh) {         // reads IN rounds mh*2 + wr
#pragma unroll
    for (int mf = 0; mf < 4; ++mf)
#pragma unroll
      for (int kk = 0; kk < 2; ++kk) {
        const int x = mh * 128 + wr * 64 + mf * 16 + lo;
        af[mf][kk] = *(const s16x8*)(lds + buf * 65536 + x * 128 +
                                     (((kk * 4 + hi) ^ (lo & 7)) << 4));
      }
  };
  auto LD_BF = [&](int buf, int nh, s16x8 (&dst)[2][2]) {  // reads W round wc
#pragma unroll
    for (int nf = 0; nf < 2; ++nf)
#pragma unroll
      for (int kk = 0; kk < 2; ++kk) {
        const int o = wc * 64 + nh * 32 + nf * 16 + lo;
        dst[nf][kk] = *(const s16x8*)(lds + buf * 65536 + 32768 + o * 128 +
                                      (((kk * 4 + hi) ^ (lo & 7)) << 4));
      }
  };

#define MMA_Q(ACC, BFR)                                                       \
  __builtin_amdgcn_s_setprio(1);                                              \
  _Pragma("unroll") for (int mf = 0; mf < 4; ++mf)                            \
  _Pragma("unroll") for (int nf = 0; nf < 2; ++nf)                            \
  _Pragma("unroll") for (int kk = 0; kk < 2; ++kk)                            \
    ACC[mf][nf] = __builtin_amdgcn_mfma_f32_16x16x32_bf16(                    \
        af[mf][kk], BFR[nf][kk], ACC[mf][nf], 0, 0, 0);                       \
  __builtin_amdgcn_s_setprio(0);

  // prologue: stage K-tile 0 in steady-state order (W0..3 then IN0..3),
  // gate vmcnt(2) (leaves IN r2,r3 in flight -> loop invariant)
#pragma unroll
  for (int r = 0; r < 4; ++r) STAGE_W(0, r);
#pragma unroll
  for (int r = 0; r < 4; ++r) STAGE_IN(0, r);
  asm volatile("s_waitcnt vmcnt(2)" ::: "memory");
  BARRIER();

  for (int kt = 0; kt < nt; ++kt) {
    const int buf = kt & 1;
    const bool pf = (kt + 1 < nt);
    // phase 1: (mh0,nh0); issue all W(kt+1)
    LD_AF(buf, 0); LD_BF(buf, 0, bfr0);
    if (pf) { STAGE_W(kt + 1, 0); STAGE_W(kt + 1, 1);
              STAGE_W(kt + 1, 2); STAGE_W(kt + 1, 3); }
    BARRIER();
    MMA_Q(acc00, bfr0);
    // phase 2: (mh0,nh1); issue all IN(kt+1); gate IN r2,r3 of kt (ancient)
    LD_BF(buf, 1, bfr1);
    if (pf) { STAGE_IN(kt + 1, 0); STAGE_IN(kt + 1, 1);
              STAGE_IN(kt + 1, 2); STAGE_IN(kt + 1, 3); }
    if (pf) asm volatile("s_waitcnt vmcnt(8)" ::: "memory");
    else    asm volatile("s_waitcnt vmcnt(0)" ::: "memory");
    BARRIER();
    MMA_Q(acc01, bfr1);
    // phase 3: (mh1,nh0) -- IN r2,r3 guaranteed; bfr0 held in regs
    LD_AF(buf, 1);
    BARRIER();
    MMA_Q(acc10, bfr0);
    // phase 4: (mh1,nh1); gate W0-3 + IN r0,r1 of kt+1 (>=2 phases cover)
    if (pf) asm volatile("s_waitcnt vmcnt(2)" ::: "memory");
    BARRIER();
    MMA_Q(acc11, bfr1);
  }
#undef MMA_Q

  // epilogue: px j = MH*128 + wr*64 + mf*16 + hi*4 + rr
  bf16* orow = (bf16*)outv + (size_t)i * 65536;
  float* orowf = (float*)outv + (size_t)i * 65536;
#define EPI_Q(ACC, MH, NH)                                                    \
  _Pragma("unroll") for (int mf = 0; mf < 4; ++mf) {                          \
    _Pragma("unroll") for (int nf = 0; nf < 2; ++nf) {                        \
      const int o = wc * 64 + NH * 32 + nf * 16 + lo;                         \
      const float bs = bias[o];                                               \
      float ni0 = 0.f, ni1 = 0.f, ni2 = 0.f;                                  \
      if (EPI) { const float* TI = TT + (size_t)i * 256 + o;                  \
        ni0 = TI[0]; ni1 = TI[65536]; ni2 = TI[2 * 65536]; }                  \
      _Pragma("unroll") for (int rr = 0; rr < 4; ++rr) {                      \
        const int j = MH * 128 + wr * 64 + mf * 16 + hi * 4 + rr;             \
        float v = ACC[mf][nf][rr] + bs;                                       \
        if (EPI) {                                                            \
          v += ni1 + (j > 0 ? ni0 : 0.f) + (j < 255 ? ni2 : 0.f);             \
          const float* TJ = TT + (size_t)3 * 65536 + (size_t)j * 256 + o;     \
          float nj0 = TJ[0], nj1 = TJ[65536], nj2 = TJ[2 * 65536];            \
          v += nj1 + (i > 0 ? nj0 : 0.f) + (i < 255 ? nj2 : 0.f); }           \
        v = fmaxf(v, 0.f);                                                    \
        if (F32OUT) orowf[(size_t)j * 256 + o] = v;                           \
        else        orow[(size_t)j * 256 + o] = f2b(v);                       \
      } } }
  EPI_Q(acc00, 0, 0); EPI_Q(acc01, 0, 1); EPI_Q(acc10, 1, 0); EPI_Q(acc11, 1, 1);
#undef EPI_Q
}

// ---------------------------------------------------------------------------
// fused: att = leaky(1x1(feat)); coeff = softmax_j; nd[i][m] = sum_j coeff*feat
template <int F32OUT>
__global__ __launch_bounds__(256) void att_wsum(const bf16* __restrict__ feat,
                                                const float* __restrict__ aw,
                                                const float* __restrict__ ab,
                                                bf16* __restrict__ ndb,
                                                float* __restrict__ ndf) {
  int i = blockIdx.x;
  int tid = threadIdx.x, lane = tid & 63, w = tid >> 6;
  __shared__ float s_aw[256];
  __shared__ float s_att[256];
  __shared__ float s_red[8];
  s_aw[tid] = aw[tid];
  __syncthreads();
  float a0 = s_aw[lane * 4], a1 = s_aw[lane * 4 + 1];
  float a2 = s_aw[lane * 4 + 2], a3 = s_aw[lane * 4 + 3];
  const bf16* fb = feat + (size_t)i * 65536;
  float abv = ab[0];
  for (int jj = 0; jj < 64; ++jj) {
    int j = w * 64 + jj;
    const bf16* f = fb + (size_t)j * 256 + lane * 4;
    float v = a0 * b2f(f[0]) + a1 * b2f(f[1]) + a2 * b2f(f[2]) + a3 * b2f(f[3]);
#pragma unroll
    for (int mk = 32; mk; mk >>= 1) v += __shfl_xor(v, mk);
    if (lane == 0) { float a = v + abv; s_att[j] = a > 0.f ? a : 0.01f * a; }
  }
  __syncthreads();
  float x = s_att[tid];
  float mx = x;
#pragma unroll
  for (int mk = 32; mk; mk >>= 1) mx = fmaxf(mx, __shfl_xor(mx, mk));
  if (lane == 0) s_red[w] = mx;
  __syncthreads();
  mx = fmaxf(fmaxf(s_red[0], s_red[1]), fmaxf(s_red[2], s_red[3]));
  float e = expf(x - mx);
  float sm = e;
#pragma unroll
  for (int mk = 32; mk; mk >>= 1) sm += __shfl_xor(sm, mk);
  if (lane == 0) s_red[4 + w] = sm;
  __syncthreads();
  sm = s_red[4] + s_red[5] + s_red[6] + s_red[7];
  __syncthreads();
  s_att[tid] = e / sm;
  __syncthreads();
  float acc = 0.f;
  for (int j = 0; j < 256; ++j) acc += s_att[j] * b2f(fb[(size_t)j * 256 + tid]);
  if (F32OUT) ndf[(size_t)i * 256 + tid] = acc;
  else        ndb[(size_t)i * 256 + tid] = f2b(acc);
}

// ---------------------------------------------------------------------------
extern "C" void kernel_launch(void* const* d_in, const int* in_sizes, int n_in,
                              void* d_out, int out_size, void* d_ws, size_t ws_size,
                              hipStream_t stream) {
  const float* edge_feats = (const float*)d_in[0];
  const float* node_feats = (const float*)d_in[1];
  const float* adapter_w  = (const float*)d_in[2];
  const float* adapter_b  = (const float*)d_in[3];
  const float* conv0_w    = (const float*)d_in[4];
  const float* conv0_b    = (const float*)d_in[5];
  const float* conv1_w    = (const float*)d_in[6];
  const float* conv1_b    = (const float*)d_in[7];
  const float* last_w     = (const float*)d_in[8];
  const float* last_b     = (const float*)d_in[9];
  const float* att_w      = (const float*)d_in[10];
  const float* att_b      = (const float*)d_in[11];
  float* out = (float*)d_out;

  char* ws = (char*)d_ws;
  size_t off = 0;
  bf16* Q   = (bf16*)(ws + off); off += (size_t)256 * 256 * 256 * 2;      // 33,554,432
  bf16* WP0 = (bf16*)(ws + off); off += (size_t)9 * 65536 * 2;
  bf16* WP1 = (bf16*)(ws + off); off += (size_t)9 * 65536 * 2;
  bf16* WP2 = (bf16*)(ws + off); off += (size_t)9 * 65536 * 2;
  bf16* WNP = (bf16*)(ws + off); off += (size_t)18 * 65536 * 2;           //  2,359,296
  float* TT = (float*)(ws + off); off += (size_t)2 * 3 * 65536 * 4;       //  1,572,864
  bf16* ND  = (bf16*)(ws + off); off += (size_t)65536 * 2;                //    131,072
  bf16* ZB  = (bf16*)(ws + off); off += 256;                              // known-safe total 41,156,864
  if (ws_size < off) {
    fill_sentinel<<<(out_size + 255) / 256, 256, 0, stream>>>(out, out_size);
    return;
  }

  zero_zb<<<1, 64, 0, stream>>>(ZB);
  pack_w<<<11520, 256, 0, stream>>>(conv0_w, conv1_w, last_w, WP0, WP1, WP2, WNP);

  for (int b = 0; b < 2; ++b) {
    // P: bf16 scratch inside the (f32) edge-out region of batch b
    bf16* P = (bf16*)(out + 131072 + (size_t)b * 16777216);
    float* edge_out = out + 131072 + (size_t)b * 16777216;
    float* node_out = out + (size_t)b * 65536;
    const float* eb = edge_feats + (size_t)b * 458752;
    const float* nb = node_feats + (size_t)b * 65536;

    adapter_k<<<256, 256, 0, stream>>>(eb, adapter_w, adapter_b, P);                 // E  @ P
    // block 1
    node_terms<float><<<384, 256, 0, stream>>>(nb, WNP, TT);
    conv3x3_k<1, 0><<<256, 512, 0, stream>>>(P, WP0, conv0_b, Q, TT, ZB);            // A  @ Q
    conv3x3_k<0, 0><<<256, 512, 0, stream>>>(Q, WP1, conv1_b, P, nullptr, ZB);       // B  @ P
    att_wsum<0><<<256, 256, 0, stream>>>(P, att_w, att_b, ND, nullptr);              // nd1 @ ND
    conv3x3_k<0, 0><<<256, 512, 0, stream>>>(P, WP2, last_b, Q, nullptr, ZB);        // C  @ Q
    // block 2
    node_terms<bf16><<<384, 256, 0, stream>>>(ND, WNP, TT);
    conv3x3_k<1, 0><<<256, 512, 0, stream>>>(Q, WP0, conv0_b, P, TT, ZB);            // D  @ P
    conv3x3_k<0, 0><<<256, 512, 0, stream>>>(P, WP1, conv1_b, Q, nullptr, ZB);       // E2 @ Q
    att_wsum<1><<<256, 256, 0, stream>>>(Q, att_w, att_b, nullptr, node_out);        // node out (f32)
    conv3x3_k<0, 1><<<256, 512, 0, stream>>>(Q, WP2, last_b, edge_out, nullptr, ZB); // edge out (f32)
  }
}